// Round 1
// 62.633 us; speedup vs baseline: 1.0593x; 1.0593x over previous
//
#include <hip/hip_runtime.h>

#define N_COLORS 131072
#define M_PAL    128
#define BLOCK    256
#define GRID     (N_COLORS / BLOCK)   // 512 blocks = 2 blocks/CU

// Stage 1: per-block partial sums of min-distance, written as plain stores to
// the workspace. No atomics: 512 same-address device-scope atomicAdds
// serialize at the coherence point and are the main controllable suspect in
// the 66 us measurement (VALU floor of this kernel is ~1.5 us).
__global__ __launch_bounds__(BLOCK) void nearest_color_partial_kernel(
    const float* __restrict__ colors,     // (N,3)
    const float* __restrict__ palette,    // (M,3)
    float* __restrict__ partials)         // (GRID,)
{
    const int tid = threadIdx.x;
    const int gid = blockIdx.x * BLOCK + tid;

    // Lane i reads 3 consecutive dwords; inputs are L2-resident (1.5 MB).
    const float r = colors[3 * gid + 0];
    const float g = colors[3 * gid + 1];
    const float b = colors[3 * gid + 2];

    // Palette is wave-uniform -> scalarized to s_load through the scalar
    // cache (verified in the previous session). Two independent min-chains
    // (even/odd j) halve the serial fminf dependency depth.
    float best0 = 3.0e38f;
    float best1 = 3.0e38f;
#pragma unroll
    for (int j = 0; j < M_PAL; j += 2) {
        {
            const float dr = r - palette[3 * j + 0];
            const float dg = g - palette[3 * j + 1];
            const float db = b - palette[3 * j + 2];
            best0 = fminf(best0, dr * dr + dg * dg + db * db);
        }
        {
            const float dr = r - palette[3 * j + 3];
            const float dg = g - palette[3 * j + 4];
            const float db = b - palette[3 * j + 5];
            best1 = fminf(best1, dr * dr + dg * dg + db * db);
        }
    }
    // min(sqrt(d)) == sqrt(min(d)): one sqrt at the end.
    float v = __builtin_sqrtf(fminf(best0, best1));

    // Wave-64 shuffle reduction.
#pragma unroll
    for (int off = 32; off > 0; off >>= 1)
        v += __shfl_down(v, off, 64);

    __shared__ float wsum[BLOCK / 64];
    if ((tid & 63) == 0) wsum[tid >> 6] = v;
    __syncthreads();

    if (tid == 0)
        partials[blockIdx.x] = wsum[0] + wsum[1] + wsum[2] + wsum[3];
}

// Stage 2: one block reduces the 512 partials and writes the scalar result
// directly. Unconditional overwrite of d_out -> the hipMemsetAsync dispatch
// (a full extra graph node) is no longer needed.
__global__ __launch_bounds__(512) void nearest_color_reduce_kernel(
    const float* __restrict__ partials,   // (GRID,)
    float* __restrict__ out)              // scalar
{
    const int tid = threadIdx.x;   // 512 threads: one partial each
    float v = partials[tid];

#pragma unroll
    for (int off = 32; off > 0; off >>= 1)
        v += __shfl_down(v, off, 64);

    __shared__ float wsum[512 / 64];
    if ((tid & 63) == 0) wsum[tid >> 6] = v;
    __syncthreads();

    if (tid == 0) {
        float s = 0.0f;
#pragma unroll
        for (int i = 0; i < 512 / 64; ++i) s += wsum[i];
        out[0] = s * (1.0f / (float)N_COLORS);
    }
}

extern "C" void kernel_launch(void* const* d_in, const int* in_sizes, int n_in,
                              void* d_out, int out_size, void* d_ws, size_t ws_size,
                              hipStream_t stream) {
    const float* colors  = (const float*)d_in[0];   // (131072, 3) fp32
    const float* palette = (const float*)d_in[1];   // (128, 3) fp32
    float* out = (float*)d_out;                     // 1 fp32 scalar
    float* partials = (float*)d_ws;                 // 512 floats (2 KB of ws)

    nearest_color_partial_kernel<<<GRID, BLOCK, 0, stream>>>(colors, palette, partials);
    nearest_color_reduce_kernel<<<1, 512, 0, stream>>>(partials, out);
}

// Round 2
// 61.349 us; speedup vs baseline: 1.0814x; 1.0209x over previous
//
#include <hip/hip_runtime.h>

#define N_COLORS 131072
#define M_PAL    128
#define BLOCK    256
#define GRID     (N_COLORS / BLOCK)   // 512 blocks = 2 blocks/CU, all co-resident

typedef unsigned long long u64;

// Single fused kernel. Each block computes a partial sum of min-distances and
// publishes it as a SELF-VALIDATING 8-byte word {bits, ~bits} via a
// device-scope atomic store. Block 0 spin-reads all 512 words (accepting only
// hi == ~lo), reduces, and writes the final scalar. This removes the second
// kernel dispatch (a full graph node) and the inter-kernel drain.
//
// Why self-validating instead of a counter: the workspace is re-poisoned
// (0xAA fill, the 40 us / 256 MiB dispatch in the profile) before every timed
// launch, so no counter has a known initial value. {x, ~x} is unreadable as
// "ready" from 0xAA poison (0xAAAAAAAA vs 0x55555555), zeroed memory, or any
// garbage except an adversarial exact pair; stale pairs from a previous
// replay carry identical correct values and are harmless.
__global__ __launch_bounds__(BLOCK) void nearest_color_loss_fused(
    const float* __restrict__ colors,     // (N,3)
    const float* __restrict__ palette,    // (M,3)
    u64* __restrict__ partials,           // (GRID,) {bits, ~bits}
    float* __restrict__ out)              // scalar
{
    const int tid = threadIdx.x;
    const int bid = blockIdx.x;
    const int gid = bid * BLOCK + tid;

    // Lane i reads 3 consecutive dwords; inputs are L2-resident (1.5 MB).
    const float r = colors[3 * gid + 0];
    const float g = colors[3 * gid + 1];
    const float b = colors[3 * gid + 2];

    // Palette reads are wave-uniform -> scalarized to s_load through the
    // scalar cache (verified in the earlier session). Two independent
    // min-chains (even/odd j) halve the serial fminf dependency depth.
    float best0 = 3.0e38f;
    float best1 = 3.0e38f;
#pragma unroll
    for (int j = 0; j < M_PAL; j += 2) {
        {
            const float dr = r - palette[3 * j + 0];
            const float dg = g - palette[3 * j + 1];
            const float db = b - palette[3 * j + 2];
            best0 = fminf(best0, dr * dr + dg * dg + db * db);
        }
        {
            const float dr = r - palette[3 * j + 3];
            const float dg = g - palette[3 * j + 4];
            const float db = b - palette[3 * j + 5];
            best1 = fminf(best1, dr * dr + dg * dg + db * db);
        }
    }
    // min(sqrt(d)) == sqrt(min(d)): one sqrt at the end.
    float v = __builtin_sqrtf(fminf(best0, best1));

    // Wave-64 shuffle reduction.
#pragma unroll
    for (int off = 32; off > 0; off >>= 1)
        v += __shfl_down(v, off, 64);

    __shared__ float wsum[BLOCK / 64];
    if ((tid & 63) == 0) wsum[tid >> 6] = v;
    __syncthreads();

    if (tid == 0) {
        const float s = wsum[0] + wsum[1] + wsum[2] + wsum[3];
        const unsigned bits = __float_as_uint(s);
        const u64 w = ((u64)(~bits) << 32) | (u64)bits;
        __hip_atomic_store(&partials[bid], w, __ATOMIC_RELAXED,
                           __HIP_MEMORY_SCOPE_AGENT);
    }

    // Block 0 finishes the reduction. Branch is block-uniform, so the
    // __syncthreads below is safe. All blocks are co-resident -> no deadlock.
    if (bid == 0) {
        float acc = 0.0f;
#pragma unroll
        for (int k = 0; k < GRID / BLOCK; ++k) {
            const int idx = k * BLOCK + tid;   // each thread claims 2 partials
            u64 w;
            do {
                w = __hip_atomic_load(&partials[idx], __ATOMIC_RELAXED,
                                      __HIP_MEMORY_SCOPE_AGENT);
            } while ((unsigned)(w >> 32) != (unsigned)(~(unsigned)w));
            acc += __uint_as_float((unsigned)w);
        }

#pragma unroll
        for (int off = 32; off > 0; off >>= 1)
            acc += __shfl_down(acc, off, 64);

        __shared__ float fsum[BLOCK / 64];
        if ((tid & 63) == 0) fsum[tid >> 6] = acc;
        __syncthreads();

        if (tid == 0)
            out[0] = (fsum[0] + fsum[1] + fsum[2] + fsum[3]) *
                     (1.0f / (float)N_COLORS);
    }
}

extern "C" void kernel_launch(void* const* d_in, const int* in_sizes, int n_in,
                              void* d_out, int out_size, void* d_ws, size_t ws_size,
                              hipStream_t stream) {
    const float* colors  = (const float*)d_in[0];   // (131072, 3) fp32
    const float* palette = (const float*)d_in[1];   // (128, 3) fp32
    float* out = (float*)d_out;                     // 1 fp32 scalar
    u64* partials = (u64*)d_ws;                     // 512 x 8 B of workspace

    nearest_color_loss_fused<<<GRID, BLOCK, 0, stream>>>(colors, palette,
                                                         partials, out);
}